// Round 1
// baseline (1541.835 us; speedup 1.0000x reference)
//
#include <hip/hip_runtime.h>
#include <cstdint>
#include <cstddef>

typedef unsigned short u16;
typedef unsigned int u32;
typedef __attribute__((ext_vector_type(8))) short bf16x8;
typedef __attribute__((ext_vector_type(4))) float f32x4;

__device__ __forceinline__ float bf2f(u16 u){ u32 x = ((u32)u)<<16; float f; __builtin_memcpy(&f,&x,4); return f; }
__device__ __forceinline__ u16 f2bf(float f){ u32 x; __builtin_memcpy(&x,&f,4); u32 r=(x+0x7FFFu+((x>>16)&1u))>>16; return (u16)r; }

// ---------------- utility kernels ----------------

__global__ void zero_bytes(uint4* p, size_t n16){
  size_t i = (size_t)blockIdx.x*blockDim.x + threadIdx.x;
  size_t st = (size_t)gridDim.x*blockDim.x;
  uint4 z; z.x=0u; z.y=0u; z.z=0u; z.w=0u;
  for (; i<n16; i+=st) p[i]=z;
}

// dst[r][c] = bf16(src[row(r)][c0+c]) with zero padding.
// gatepad: dst row r -> src row (r>>8)*254 + (r&255), valid only if (r&255)<254
__global__ void pad_convert(const float* __restrict__ src, int src_ld, int c0, int vcols, int gatepad,
                            u16* __restrict__ dst, int drows, int dcols){
  int i = blockIdx.x*256 + threadIdx.x;
  int tot = drows*dcols;
  if (i >= tot) return;
  int r = i/dcols, c = i - r*dcols;
  float v = 0.f;
  if (gatepad){
    int jj = r & 255;
    if (jj < 254 && c < vcols) v = src[(size_t)((r>>8)*254 + jj)*src_ld + c0 + c];
  } else {
    if (c < vcols) v = src[(size_t)r*src_ld + c0 + c];
  }
  dst[i] = f2bf(v);
}

__global__ void pad_bias(const float* __restrict__ src, float* __restrict__ dst){
  int r = blockIdx.x*256 + threadIdx.x;
  if (r >= 768) return;
  int jj = r & 255;
  dst[r] = (jj<254) ? src[(r>>8)*254 + jj] : 0.f;
}

__global__ void gather_enc(const int* __restrict__ idx, const float* __restrict__ emb, u16* __restrict__ dst){
  int i = blockIdx.x*256 + threadIdx.x;  // 3200*128
  int r = i>>7, k = i&127;
  dst[i] = f2bf(emb[(size_t)idx[r]*128 + k]);
}

__global__ void gather_dec(const int* __restrict__ idx, const float* __restrict__ emb,
                           u16* __restrict__ dst, u16* __restrict__ feat){
  int i = blockIdx.x*256 + threadIdx.x;  // 3200*128
  int r = i>>7, k = i&127;
  u16 v = 0;
  if (r < 3136) v = f2bf(emb[(size_t)idx[r]*128 + k]);
  dst[i] = v;
  if (r < 3136) feat[(size_t)r*640 + 508 + k] = v;
}

// ---------------- bf16 MFMA GEMM: C = A(MxK) * B(NxK)^T + bias ----------------
// BM=BN=128, BK=64, 256 threads (4 waves, 2x2), 4x4 16x16x32 frags per wave.

__global__ __launch_bounds__(256) void gemm_bt(
  const u16* __restrict__ A, int lda,
  const u16* __restrict__ B, int ldb,
  float* __restrict__ C, long long ldc,
  const float* __restrict__ bias,
  int K, int Mtiles, int Mstore)
{
  __shared__ __align__(16) u16 Al[128*64];
  __shared__ __align__(16) u16 Bl[128*64];
  const int t = threadIdx.x;
  const int w = t>>6, l = t&63;
  const int wm = w>>1, wn = w&1;
  const int bid = blockIdx.x;
  const int mt = bid % Mtiles, nt = bid / Mtiles;
  const int m0 = mt<<7, n0 = nt<<7;
  const int c8 = (t&7)*8;   // k-chunk offset (elements)
  const int r0 = t>>3;      // 0..31 row within 32-row group

  f32x4 acc[4][4] = {};

  const int ksteps = K>>6;
  for (int ks=0; ks<ksteps; ++ks){
    const int k0 = ks<<6;
    uint4 va[4], vb[4];
    #pragma unroll
    for (int i=0;i<4;++i){
      const int r = i*32 + r0;
      va[i] = *(const uint4*)(A + (size_t)(m0+r)*lda + k0 + c8);
      vb[i] = *(const uint4*)(B + (size_t)(n0+r)*ldb + k0 + c8);
    }
    __syncthreads();
    #pragma unroll
    for (int i=0;i<4;++i){
      const int r = i*32 + r0;
      *(uint4*)&Al[(size_t)r*64 + c8] = va[i];
      *(uint4*)&Bl[(size_t)r*64 + c8] = vb[i];
    }
    __syncthreads();
    #pragma unroll
    for (int kk=0;kk<2;++kk){
      const int ko = kk*32 + (l>>4)*8;
      bf16x8 af[4], bfr[4];
      #pragma unroll
      for (int m=0;m<4;++m) af[m] = *(const bf16x8*)&Al[(wm*64+m*16+(l&15))*64 + ko];
      #pragma unroll
      for (int n=0;n<4;++n) bfr[n] = *(const bf16x8*)&Bl[(wn*64+n*16+(l&15))*64 + ko];
      #pragma unroll
      for (int m=0;m<4;++m)
        #pragma unroll
        for (int n=0;n<4;++n)
          acc[m][n] = __builtin_amdgcn_mfma_f32_16x16x32_bf16(af[m], bfr[n], acc[m][n], 0,0,0);
    }
  }

  #pragma unroll
  for (int m=0;m<4;++m){
    const int rb = m0 + wm*64 + m*16 + (l>>4)*4;
    #pragma unroll
    for (int n=0;n<4;++n){
      const int col = n0 + wn*64 + n*16 + (l&15);
      const float bv = bias[col];
      #pragma unroll
      for (int r=0;r<4;++r){
        const int rr = rb + r;
        if (rr < Mstore) C[(size_t)rr*ldc + col] = acc[m][n][r] + bv;
      }
    }
  }
}

// ---------------- persistent GRU scan kernel ----------------
// 16 blocks x 256 threads. Block g owns hidden units [16g,16g+16) (H padded to 256).
// W_hh fragments live in registers; h state ping-pongs in global as bf16.

__global__ __launch_bounds__(256,1) void scan_kernel(
  const u16* __restrict__ Whhe, const u16* __restrict__ Whhd, const u16* __restrict__ Wihdc,
  const float* __restrict__ bhhe, const float* __restrict__ bhhd,
  const float* __restrict__ enc_gi, const float* __restrict__ dec_gi,
  u16* __restrict__ hglob, u16* __restrict__ feat, u32* __restrict__ ctr)
{
  const int t = threadIdx.x, g = blockIdx.x;
  const int w = t>>6, l = t&63;
  const int jl = l&15, q = l>>4;
  const int j = g*16 + jl;          // unit index in [0,256)
  const int arow = w*16 + jl;       // batch row read for A-fragments

  bf16x8 Bf[3][8];

  auto loadW = [&](const u16* W){
    #pragma unroll
    for (int s3=0;s3<3;++s3)
      #pragma unroll
      for (int kk=0;kk<8;++kk)
        Bf[s3][kk] = *(const bf16x8*)&W[(size_t)(s3*256 + g*16 + jl)*256 + kk*32 + q*8];
  };

  auto bar = [&](){
    __threadfence();
    __syncthreads();
    if (t==0){
      u32 old = atomicAdd(ctr,1u);
      u32 tgt = (old/16u+1u)*16u;
      while (atomicAdd(ctr,0u) < tgt) __builtin_amdgcn_s_sleep(1);
    }
    __syncthreads();
    __threadfence();
  };

  auto mm = [&](const u16* hsrc, f32x4* acc3){
    bf16x8 a[8];
    #pragma unroll
    for (int kk=0;kk<8;++kk)
      a[kk] = *(const bf16x8*)&hsrc[arow*256 + kk*32 + q*8];
    #pragma unroll
    for (int s3=0;s3<3;++s3)
      #pragma unroll
      for (int kk=0;kk<8;++kk)
        acc3[s3] = __builtin_amdgcn_mfma_f32_16x16x32_bf16(a[kk], Bf[s3][kk], acc3[s3], 0,0,0);
  };

  // ---- encoder: 50 steps ----
  loadW(Whhe);
  const float bhr_e=bhhe[j], bhz_e=bhhe[256+j], bhn_e=bhhe[512+j];
  #pragma unroll 1
  for (int s=0; s<50; ++s){
    const int cur = s&1;
    const u16* hsrc = hglob + cur*16384;
    u16* hdst = hglob + (cur^1)*16384;
    f32x4 acc3[3] = {};
    mm(hsrc, acc3);
    #pragma unroll
    for (int r=0;r<4;++r){
      const int b = w*16 + q*4 + r;
      const float* gi = enc_gi + (size_t)(s*64+b)*768;
      float ghr = acc3[0][r]+bhr_e, ghz = acc3[1][r]+bhz_e, ghn = acc3[2][r]+bhn_e;
      float ho = bf2f(hsrc[b*256 + j]);
      float rg = 1.f/(1.f+__expf(-(gi[j]+ghr)));
      float zg = 1.f/(1.f+__expf(-(gi[256+j]+ghz)));
      float ng = tanhf(gi[512+j] + rg*ghn);
      float h2 = (1.f-zg)*ng + zg*ho;
      hdst[b*256+j] = f2bf(h2);
    }
    bar();
  }

  // context now in hglob[0] (50 steps: buffer returns to 0)
  // ---- context-dependent decoder gate input (step-invariant) -> registers ----
  loadW(Wihdc);
  f32x4 ctxv[3] = {};
  mm(hglob, ctxv);

  // ---- fill feat context columns [254,508) ----
  if (j < 254){
    #pragma unroll 1
    for (int tt=0; tt<49; ++tt){
      #pragma unroll
      for (int r=0;r<4;++r){
        const int b = w*16 + q*4 + r;
        feat[(size_t)(tt*64+b)*640 + 254 + j] = hglob[b*256+j];
      }
    }
  }

  // ---- decoder: 49 steps, h0 = context ----
  loadW(Whhd);
  const float bhr_d=bhhd[j], bhz_d=bhhd[256+j], bhn_d=bhhd[512+j];
  #pragma unroll 1
  for (int tt=0; tt<49; ++tt){
    const int cur = tt&1;
    const u16* hsrc = hglob + cur*16384;
    u16* hdst = hglob + (cur^1)*16384;
    f32x4 acc3[3] = {};
    mm(hsrc, acc3);
    #pragma unroll
    for (int r=0;r<4;++r){
      const int b = w*16 + q*4 + r;
      const float* gi = dec_gi + (size_t)(tt*64+b)*768;
      float ghr = acc3[0][r]+bhr_d, ghz = acc3[1][r]+bhz_d, ghn = acc3[2][r]+bhn_d;
      float ho = bf2f(hsrc[b*256+j]);
      float rg = 1.f/(1.f+__expf(-(gi[j]     + ctxv[0][r] + ghr)));
      float zg = 1.f/(1.f+__expf(-(gi[256+j] + ctxv[1][r] + ghz)));
      float ng = tanhf(   gi[512+j] + ctxv[2][r] + rg*ghn);
      float h2 = (1.f-zg)*ng + zg*ho;
      hdst[b*256+j] = f2bf(h2);
      if (j < 254) feat[(size_t)(tt*64+b)*640 + j] = f2bf(h2);
    }
    bar();
  }
}

// ---------------- launch ----------------

extern "C" void kernel_launch(void* const* d_in, const int* in_sizes, int n_in,
                              void* d_out, int out_size, void* d_ws, size_t ws_size,
                              hipStream_t stream) {
  const int*   src     = (const int*)d_in[0];
  const int*   trg     = (const int*)d_in[1];
  const float* emb_enc = (const float*)d_in[2];
  const float* W_ih_e  = (const float*)d_in[3];
  const float* W_hh_e  = (const float*)d_in[4];
  const float* b_ih_e  = (const float*)d_in[5];
  const float* b_hh_e  = (const float*)d_in[6];
  const float* emb_dec = (const float*)d_in[7];
  const float* W_ih_d  = (const float*)d_in[8];
  const float* W_hh_d  = (const float*)d_in[9];
  const float* b_ih_d  = (const float*)d_in[10];
  const float* b_hh_d  = (const float*)d_in[11];
  const float* W_out   = (const float*)d_in[12];
  const float* b_out   = (const float*)d_in[13];
  float* out = (float*)d_out;

  char* basep = (char*)d_ws;
  size_t off = 0;
  auto take = [&](size_t b)->char*{ char* p = basep + off; off = (off + b + 255) & ~(size_t)255; return p; };
  u16* feat    = (u16*)take(4096000);   // [3200][640] bf16
  u16* hglob   = (u16*)take(65536);     // [2][64][256] bf16
  u32* ctr     = (u32*)take(256);
  u16* wout_b  = (u16*)take(40960000);  // [32000][640]
  u16* wihe_b  = (u16*)take(196608);    // [768][128]
  u16* wihde_b = (u16*)take(196608);    // [768][128]
  u16* wihdc_b = (u16*)take(393216);    // [768][256]
  u16* whhe_b  = (u16*)take(393216);    // [768][256]
  u16* whhd_b  = (u16*)take(393216);    // [768][256]
  u16* encx_b  = (u16*)take(819200);    // [3200][128]
  u16* dece_b  = (u16*)take(819200);    // [3200][128]
  float* enc_gi = (float*)take(9830400);  // [3200][768]
  float* dec_gi = (float*)take(9830400);  // [3200][768]
  float* bihe_p = (float*)take(3072);
  float* bihd_p = (float*)take(3072);
  float* bhhe_p = (float*)take(3072);
  float* bhhd_p = (float*)take(3072);
  (void)in_sizes; (void)n_in; (void)out_size; (void)ws_size;

  // zero: feat+hglob+ctr (contiguous 4161792 B), and output row 0 (8192000 B)
  zero_bytes<<<512, 256, 0, stream>>>((uint4*)feat, (size_t)(4161792/16));
  zero_bytes<<<2000, 256, 0, stream>>>((uint4*)out, (size_t)(8192000/16));

  auto PC = [&](const float* s, int sld, int c0, int vc, int gp, u16* d, int dr, int dc){
    int tot = dr*dc;
    pad_convert<<<(tot+255)/256, 256, 0, stream>>>(s, sld, c0, vc, gp, d, dr, dc);
  };
  PC(W_ih_e, 128,   0, 128, 1, wihe_b,  768, 128);
  PC(W_ih_d, 382,   0, 128, 1, wihde_b, 768, 128);
  PC(W_ih_d, 382, 128, 254, 1, wihdc_b, 768, 256);
  PC(W_hh_e, 254,   0, 254, 1, whhe_b,  768, 256);
  PC(W_hh_d, 254,   0, 254, 1, whhd_b,  768, 256);
  PC(W_out,  636,   0, 636, 0, wout_b, 32000, 640);

  pad_bias<<<3, 256, 0, stream>>>(b_ih_e, bihe_p);
  pad_bias<<<3, 256, 0, stream>>>(b_ih_d, bihd_p);
  pad_bias<<<3, 256, 0, stream>>>(b_hh_e, bhhe_p);
  pad_bias<<<3, 256, 0, stream>>>(b_hh_d, bhhd_p);

  gather_enc<<<1600, 256, 0, stream>>>(src, emb_enc, encx_b);
  gather_dec<<<1600, 256, 0, stream>>>(trg, emb_dec, dece_b, feat);

  // gi = x @ W_ih^T + b  (M=3200, N=768, K=128)
  gemm_bt<<<25*6, 256, 0, stream>>>(encx_b, 128, wihe_b, 128, enc_gi, (long long)768, bihe_p, 128, 25, 3200);
  gemm_bt<<<25*6, 256, 0, stream>>>(dece_b, 128, wihde_b, 128, dec_gi, (long long)768, bihd_p, 128, 25, 3200);

  // sequential GRU scans (enc 50 + dec 49 steps)
  scan_kernel<<<16, 256, 0, stream>>>(whhe_b, whhd_b, wihdc_b, bhhe_p, bhhd_p,
                                      enc_gi, dec_gi, hglob, feat, ctr);

  // out[1..49] = feat @ W_out^T + b_out  (M=3200 pad, N=32000, K=640)
  gemm_bt<<<25*250, 256, 0, stream>>>(feat, 640, wout_b, 640, out + (size_t)64*32000, (long long)32000, b_out, 640, 25, 3136);
}